// Round 1
// baseline (211.299 us; speedup 1.0000x reference)
//
#include <hip/hip_runtime.h>
#include <hip/hip_bf16.h>

// AdaGuidedFilter: x:(4,64,256,256) f32 -> out same shape.
// out = x * (A*x + (1-A)*mean), A = var/(var+eps),
// mean/var from 11x11 zero-padded box sums normalized by in-window count.

#define RAD   5
#define KW    11
#define IMG_H 256
#define IMG_W 256
#define TILE_H 32
#define IN_H  (TILE_H + 2 * RAD)   // 42
#define EPS_F 0.01f

__global__ __launch_bounds__(256)
void AdaGuidedFilter_17686675325295_kernel(const float* __restrict__ x,
                                           float* __restrict__ out) {
    __shared__ float xs [IN_H][IMG_W];
    __shared__ float hs [IN_H][IMG_W];
    __shared__ float hs2[IN_H][IMG_W];

    const int bid   = blockIdx.x;
    const int img   = bid >> 3;          // 256 images
    const int strip = bid & 7;           // 8 strips of 32 rows
    const int tid   = threadIdx.x;       // column 0..255

    const float* __restrict__ xim = x   + (size_t)img * IMG_H * IMG_W;
    float* __restrict__       oim = out + (size_t)img * IMG_H * IMG_W;

    const int row0 = strip * TILE_H - RAD;  // global row of local row 0

    // ---- stage input strip (zero-padded rows) ----
    #pragma unroll
    for (int li = 0; li < IN_H; ++li) {
        const int g = row0 + li;
        xs[li][tid] = (g >= 0 && g < IMG_H) ? xim[g * IMG_W + tid] : 0.0f;
    }
    __syncthreads();

    // ---- horizontal 11-tap sums of x and x^2 ----
    for (int idx = tid; idx < IN_H * IMG_W; idx += 256) {
        const int li = idx >> 8;
        const int c  = idx & 255;
        float s = 0.0f, s2 = 0.0f;
        #pragma unroll
        for (int d = -RAD; d <= RAD; ++d) {
            const int cc = c + d;
            if (cc >= 0 && cc < IMG_W) {
                const float v = xs[li][cc];
                s  += v;
                s2 += v * v;
            }
        }
        hs [li][c] = s;
        hs2[li][c] = s2;
    }
    __syncthreads();

    // ---- vertical sliding window + epilogue (one column per thread) ----
    const int c   = tid;
    const int wlo = (c - RAD < 0) ? 0 : c - RAD;
    const int whi = (c + RAD > IMG_W - 1) ? IMG_W - 1 : c + RAD;
    const float wcnt = (float)(whi - wlo + 1);

    float vs = 0.0f, vs2 = 0.0f;
    #pragma unroll
    for (int li = 0; li < KW; ++li) {
        vs  += hs [li][c];
        vs2 += hs2[li][c];
    }

    for (int ro = 0; ro < TILE_H; ++ro) {
        const int gr  = strip * TILE_H + ro;
        const int rlo = (gr - RAD < 0) ? 0 : gr - RAD;
        const int rhi = (gr + RAD > IMG_H - 1) ? IMG_H - 1 : gr + RAD;
        const float cnt  = (float)(rhi - rlo + 1) * wcnt;
        const float inv  = 1.0f / cnt;

        const float mean = vs  * inv;
        const float m2   = vs2 * inv;
        const float var  = m2 - mean * mean;
        const float A    = var / (var + EPS_F);
        const float b    = (1.0f - A) * mean;
        const float xv   = xs[ro + RAD][c];

        oim[gr * IMG_W + c] = xv * (A * xv + b);

        if (ro < TILE_H - 1) {
            vs  += hs [ro + KW][c] - hs [ro][c];
            vs2 += hs2[ro + KW][c] - hs2[ro][c];
        }
    }
}

extern "C" void kernel_launch(void* const* d_in, const int* in_sizes, int n_in,
                              void* d_out, int out_size, void* d_ws, size_t ws_size,
                              hipStream_t stream) {
    (void)in_sizes; (void)n_in; (void)d_ws; (void)ws_size; (void)out_size;
    const float* x = (const float*)d_in[0];
    float* out = (float*)d_out;
    // 4*64 = 256 images, 8 strips each
    dim3 grid(256 * 8);
    dim3 block(256);
    AdaGuidedFilter_17686675325295_kernel<<<grid, block, 0, stream>>>(x, out);
}

// Round 2
// 51.766 us; speedup vs baseline: 4.0818x; 4.0818x over previous
//
#include <hip/hip_runtime.h>
#include <hip/hip_bf16.h>

// AdaGuidedFilter: x:(4,64,256,256) f32 -> out same shape.
// out = x * (A*x + (1-A)*mean), A = var/(var+eps),
// mean/var from 11x11 zero-padded box sums normalized by in-window count.
//
// R2 structure: vertical-first in registers (26-row strip per column),
// packed float2 vertical sums in 32 KB LDS, horizontal 11-tap on the fly.
// LDS 129KB->32KB lifts occupancy 4/CU -> 20 waves/CU.

#define RAD    5
#define KW     11
#define IMG_H  256
#define IMG_W  256
#define TILE_H 16
#define IN_H   (TILE_H + 2 * RAD)   // 26
#define STRIPS (IMG_H / TILE_H)     // 16
#define EPS_F  0.01f

__global__ __launch_bounds__(256)
void AdaGuidedFilter_17686675325295_kernel(const float* __restrict__ x,
                                           float* __restrict__ out) {
    __shared__ float2 vsum[TILE_H][IMG_W];   // .x = sum x, .y = sum x^2  (32 KB)

    // XCD-chunked swizzle: consecutive logical blocks (same image's strips)
    // land on the same XCD -> halo rows shared via that XCD's L2.
    // nwg = 4096, 8 XCDs, 512 per XCD; bijective since 4096 % 8 == 0.
    const int d   = blockIdx.x;
    const int L   = (d & 7) * (STRIPS * 256 / 8) + (d >> 3);
    const int img   = L >> 4;           // 0..255
    const int strip = L & (STRIPS - 1); // 0..15
    const int c   = threadIdx.x;        // column 0..255

    const float* __restrict__ xim = x   + (size_t)img * IMG_H * IMG_W;
    float* __restrict__       oim = out + (size_t)img * IMG_H * IMG_W;

    const int row0 = strip * TILE_H - RAD;   // global row of register-strip idx 0

    // ---- load 26-row column strip into registers (zero-padded) ----
    float xr[IN_H];
    #pragma unroll
    for (int li = 0; li < IN_H; ++li) {
        const int g = row0 + li;
        xr[li] = (g >= 0 && g < IMG_H) ? xim[g * IMG_W + c] : 0.0f;
    }

    // ---- vertical 11-row sliding sums of x and x^2 (registers) ----
    float vs = 0.0f, vs2 = 0.0f;
    #pragma unroll
    for (int li = 0; li < KW; ++li) {
        vs  += xr[li];
        vs2 += xr[li] * xr[li];
    }
    #pragma unroll
    for (int ro = 0; ro < TILE_H; ++ro) {
        vsum[ro][c] = make_float2(vs, vs2);
        if (ro < TILE_H - 1) {
            const float a = xr[ro + KW], s = xr[ro];
            vs  += a - s;
            vs2 += a * a - s * s;
        }
    }
    __syncthreads();

    // ---- horizontal 11-tap from LDS + analytic count + epilogue ----
    const int wlo = (c - RAD < 0) ? 0 : c - RAD;
    const int whi = (c + RAD > IMG_W - 1) ? IMG_W - 1 : c + RAD;
    const float wcnt = (float)(whi - wlo + 1);

    #pragma unroll 2
    for (int ro = 0; ro < TILE_H; ++ro) {
        float s = 0.0f, s2 = 0.0f;
        #pragma unroll
        for (int dd = -RAD; dd <= RAD; ++dd) {
            const int cc = c + dd;
            if (cc >= 0 && cc < IMG_W) {
                const float2 v = vsum[ro][cc];
                s  += v.x;
                s2 += v.y;
            }
        }
        const int gr  = strip * TILE_H + ro;
        const int rlo = (gr - RAD < 0) ? 0 : gr - RAD;
        const int rhi = (gr + RAD > IMG_H - 1) ? IMG_H - 1 : gr + RAD;
        const float inv = 1.0f / ((float)(rhi - rlo + 1) * wcnt);

        const float mean = s  * inv;
        const float m2   = s2 * inv;
        const float var  = m2 - mean * mean;
        const float A    = var / (var + EPS_F);
        const float b    = (1.0f - A) * mean;
        const float xv   = xr[ro + RAD];

        oim[gr * IMG_W + c] = xv * (A * xv + b);
    }
}

extern "C" void kernel_launch(void* const* d_in, const int* in_sizes, int n_in,
                              void* d_out, int out_size, void* d_ws, size_t ws_size,
                              hipStream_t stream) {
    (void)in_sizes; (void)n_in; (void)d_ws; (void)ws_size; (void)out_size;
    const float* x = (const float*)d_in[0];
    float* out = (float*)d_out;
    dim3 grid(256 * STRIPS);   // 4096 blocks
    dim3 block(256);
    AdaGuidedFilter_17686675325295_kernel<<<grid, block, 0, stream>>>(x, out);
}

// Round 3
// 43.011 us; speedup vs baseline: 4.9127x; 1.2036x over previous
//
#include <hip/hip_runtime.h>
#include <hip/hip_bf16.h>

// AdaGuidedFilter: x:(4,64,256,256) f32 -> out same shape.
// out = x * (A*x + (1-A)*mean), A = var/(var+eps),
// mean/var from 11x11 zero-padded box sums normalized by in-window count.
//
// R3: both passes are sliding windows.
//  phase 1: thread-per-column, vertical 11-row sliding sums -> LDS (XOR-swizzled, 32 KB)
//  phase 2: thread-per-(row,16-col-segment), horizontal sliding window,
//           float4 x prefetch + float4 stores (coalesced), v_rcp epilogue.

#define RAD    5
#define KW     11
#define IMG_H  256
#define IMG_W  256
#define TILE_H 16
#define IN_H   (TILE_H + 2 * RAD)   // 26
#define STRIPS (IMG_H / TILE_H)     // 16
#define EPS_F  0.01f

__global__ __launch_bounds__(256, 5)
void AdaGuidedFilter_17686675325295_kernel(const float* __restrict__ x,
                                           float* __restrict__ out) {
    // element (r,c) stored at r*256 + (c ^ r); XOR kills the 16-way bank
    // conflict of the phase-2 read pattern (16 row-lanes, same column).
    __shared__ float2 vsum[TILE_H * IMG_W];   // 32768 B -> 5 blocks/CU

    // XCD-chunked swizzle (4096 % 8 == 0 -> bijective)
    const int d     = blockIdx.x;
    const int L     = (d & 7) * ((256 * STRIPS) / 8) + (d >> 3);
    const int img   = L >> 4;
    const int strip = L & (STRIPS - 1);
    const int tid   = threadIdx.x;

    const float* __restrict__ xim = x   + (size_t)img * (IMG_H * IMG_W);
    float* __restrict__       oim = out + (size_t)img * (IMG_H * IMG_W);

    // ---- phase-2 coordinates (row-segment mapping): ro fastest within wave ----
    const int ro  = tid & 15;        // row within tile
    const int seg = tid >> 4;        // 16-column segment
    const int gr  = strip * TILE_H + ro;
    const int c0  = seg * 16;

    // prefetch epilogue x (16 floats = 4x float4, 64B/thread, coalesced);
    // completes under phase-1 compute + barrier.
    float xv[16];
    {
        const float4* xrow = reinterpret_cast<const float4*>(xim + (size_t)gr * IMG_W + c0);
        #pragma unroll
        for (int j = 0; j < 4; ++j) {
            const float4 q = xrow[j];
            xv[4*j+0] = q.x; xv[4*j+1] = q.y; xv[4*j+2] = q.z; xv[4*j+3] = q.w;
        }
    }

    // ---- phase 1: vertical 11-row sliding sums, thread per column ----
    {
        const int c    = tid;
        const int row0 = strip * TILE_H - RAD;
        float xr[IN_H];
        #pragma unroll
        for (int li = 0; li < IN_H; ++li) {
            const int g = row0 + li;
            xr[li] = (g >= 0 && g < IMG_H) ? xim[(size_t)g * IMG_W + c] : 0.0f;
        }
        float s = 0.0f, s2 = 0.0f;
        #pragma unroll
        for (int li = 0; li < KW; ++li) { s += xr[li]; s2 += xr[li] * xr[li]; }
        #pragma unroll
        for (int r = 0; r < TILE_H; ++r) {
            vsum[(r << 8) | (c ^ r)] = make_float2(s, s2);
            if (r < TILE_H - 1) {
                const float a = xr[r + KW], b = xr[r];
                s  += a - b;
                s2 += a * a - b * b;
            }
        }
    }
    __syncthreads();

    // ---- phase 2: horizontal sliding window + epilogue ----
    const int rlo = (gr - RAD < 0) ? 0 : gr - RAD;
    const int rhi = (gr + RAD > IMG_H - 1) ? IMG_H - 1 : gr + RAD;
    const float rcnt = (float)(rhi - rlo + 1);

    float s = 0.0f, s2 = 0.0f;
    #pragma unroll
    for (int dd = -RAD; dd <= RAD; ++dd) {
        const int cc = c0 + dd;
        if (cc >= 0 && cc < IMG_W) {
            const float2 v = vsum[(ro << 8) | (cc ^ ro)];
            s += v.x; s2 += v.y;
        }
    }

    float o[16];
    #pragma unroll
    for (int i = 0; i < 16; ++i) {
        const int c   = c0 + i;
        const int wlo = (c - RAD < 0) ? 0 : c - RAD;
        const int whi = (c + RAD > IMG_W - 1) ? IMG_W - 1 : c + RAD;
        const float inv  = __builtin_amdgcn_rcpf(rcnt * (float)(whi - wlo + 1));
        const float mean = s  * inv;
        const float m2   = s2 * inv;
        const float var  = m2 - mean * mean;
        const float A    = var * __builtin_amdgcn_rcpf(var + EPS_F);
        const float b    = (1.0f - A) * mean;
        const float xq   = xv[i];
        o[i] = xq * (A * xq + b);
        if (i < 15) {   // slide window c -> c+1: add c+6, drop c-5
            const int ca = c + RAD + 1;
            const int cs = c - RAD;
            if (ca < IMG_W) { const float2 v = vsum[(ro << 8) | (ca ^ ro)]; s += v.x; s2 += v.y; }
            if (cs >= 0)    { const float2 v = vsum[(ro << 8) | (cs ^ ro)]; s -= v.x; s2 -= v.y; }
        }
    }

    // coalesced float4 stores (64B/thread run)
    float4* orow = reinterpret_cast<float4*>(oim + (size_t)gr * IMG_W + c0);
    #pragma unroll
    for (int j = 0; j < 4; ++j) {
        orow[j] = make_float4(o[4*j+0], o[4*j+1], o[4*j+2], o[4*j+3]);
    }
}

extern "C" void kernel_launch(void* const* d_in, const int* in_sizes, int n_in,
                              void* d_out, int out_size, void* d_ws, size_t ws_size,
                              hipStream_t stream) {
    (void)in_sizes; (void)n_in; (void)d_ws; (void)ws_size; (void)out_size;
    const float* x = (const float*)d_in[0];
    float* out = (float*)d_out;
    dim3 grid(256 * STRIPS);   // 4096 blocks
    dim3 block(256);
    AdaGuidedFilter_17686675325295_kernel<<<grid, block, 0, stream>>>(x, out);
}